// Round 1
// baseline (70.191 us; speedup 1.0000x reference)
//
#include <hip/hip_runtime.h>

#if __has_builtin(__builtin_amdgcn_exp2f)
__device__ __forceinline__ float fast_exp2(float x) { return __builtin_amdgcn_exp2f(x); }
#else
__device__ __forceinline__ float fast_exp2(float x) { return exp2f(x); }
#endif

constexpr int C_ = 256;   // centers
constexpr int M_ = 5;     // ensemble size
constexpr float LOG2E = 1.4426950408889634f;

// out[m,n,d] = sum_c exp(-||x_n - c||^2) * sigma^2 * W[m,c,d],  sigma^2 = 1/16
//
// Algebraic refactor (saves 3 VALU ops per (n,c) pair):
//   exp(-d2)/16 = 2^(-L*|x|^2) * 2^(2L*(x.c)) * 2^(-L*|c|^2 - 4),  L = log2(e)
//   - 2^(-L*|c|^2-4) is folded into the weights at staging time (w' = w*e^{-c2}/16)
//   - 2^(-L*|x|^2)   is applied as one per-n scale after the reduction
//   - inner loop per pair: 1 mul + 1 fma + 1 exp2 + 10 fma   (was 16 instrs)
// Ranges: overall exponent == -L*d2-4 <= -4; the intermediate 2^(2L*x.c)*w'
// is bounded by e^{|x|^2}*w (~1e11 worst case) — safely inside fp32.
//
// Block = 256 threads = 64 n  x  4 c-chunks (one wave per chunk; c is
// wave-uniform so all LDS table reads are broadcasts).
// __launch_bounds__(256, 8): cap at 64 VGPR so 8 waves/SIMD -> all ~1563
// blocks resident in a single pass (grid/CU ~= 6.1).
__global__ __launch_bounds__(256, 8) void ensemble_rbf_kernel(
    const float* __restrict__ x,        // [N,2]
    const float* __restrict__ centers,  // [256,2]
    const float* __restrict__ weights,  // [5,256,2]
    float* __restrict__ out,            // [5,N,2]
    int N)
{
    // packed table: per center c, 12 floats {ux, uy, w'0..w'9}, 48B row.
    // reused after the main loop as the reduction scratch [4][64][12].
    __shared__ float s_tab[C_ * 12];

    const int tid   = threadIdx.x;
    const int nl    = tid & 63;     // local n (lane)
    const int chunk = tid >> 6;     // wave id = c-chunk

    // ---- stage packed table: thread t fills row t ----
    {
        float2 cv = ((const float2*)centers)[tid];
        float c2  = fmaf(cv.x, cv.x, cv.y * cv.y);
        float s   = fast_exp2(fmaf(c2, -LOG2E, -4.0f));   // e^{-|c|^2} / 16
        float* row = &s_tab[tid * 12];
        row[0] = (2.0f * LOG2E) * cv.x;                   // ux
        row[1] = (2.0f * LOG2E) * cv.y;                   // uy
        const float2* w2 = (const float2*)weights;        // [5][256] float2
        #pragma unroll
        for (int m = 0; m < M_; m++) {
            float2 wv = w2[m * C_ + tid];                 // coalesced
            row[2 + 2 * m]     = wv.x * s;                // w' = w * e^{-c2}/16
            row[2 + 2 * m + 1] = wv.y * s;
        }
    }
    __syncthreads();

    const int n = blockIdx.x * 64 + nl;
    float2 xv = (n < N) ? ((const float2*)x)[n] : make_float2(0.f, 0.f);

    float acc[2 * M_];
    #pragma unroll
    for (int i = 0; i < 2 * M_; i++) acc[i] = 0.f;

    const float4* tab4 = (const float4*)s_tab;
    const int cbase = chunk * 64;

    #pragma unroll 4
    for (int cc = 0; cc < 64; cc++) {
        int c = cbase + cc;                 // wave-uniform
        float4 t0 = tab4[c * 3 + 0];        // {ux, uy, w'0, w'1}
        float4 t1 = tab4[c * 3 + 1];        // {w'2, w'3, w'4, w'5}
        float4 t2 = tab4[c * 3 + 2];        // {w'6, w'7, w'8, w'9}

        // r = 2^(2L * x.c)
        float r = fast_exp2(fmaf(xv.y, t0.y, xv.x * t0.x));

        acc[0] = fmaf(r, t0.z, acc[0]);  acc[1] = fmaf(r, t0.w, acc[1]);
        acc[2] = fmaf(r, t1.x, acc[2]);  acc[3] = fmaf(r, t1.y, acc[3]);
        acc[4] = fmaf(r, t1.z, acc[4]);  acc[5] = fmaf(r, t1.w, acc[5]);
        acc[6] = fmaf(r, t2.x, acc[6]);  acc[7] = fmaf(r, t2.y, acc[7]);
        acc[8] = fmaf(r, t2.z, acc[8]);  acc[9] = fmaf(r, t2.w, acc[9]);
    }

    // ---- combine the 4 chunk-partials per n via LDS ----
    __syncthreads();   // everyone done reading the table
    {
        float4* slot = (float4*)&s_tab[(chunk * 64 + nl) * 12];
        slot[0] = make_float4(acc[0], acc[1], acc[2], acc[3]);
        slot[1] = make_float4(acc[4], acc[5], acc[6], acc[7]);
        slot[2] = make_float4(acc[8], acc[9], 0.f, 0.f);
    }
    __syncthreads();

    if (tid < 64 && n < N) {
        // chunk==0 here, so this thread's xv is exactly x[n] for its n.
        float4 s0 = make_float4(0.f, 0.f, 0.f, 0.f);
        float4 s1 = s0, s2 = s0;
        #pragma unroll
        for (int k = 0; k < 4; k++) {
            const float4* slot = (const float4*)&s_tab[(k * 64 + nl) * 12];
            float4 r0 = slot[0], r1 = slot[1], r2 = slot[2];
            s0.x += r0.x; s0.y += r0.y; s0.z += r0.z; s0.w += r0.w;
            s1.x += r1.x; s1.y += r1.y; s1.z += r1.z; s1.w += r1.w;
            s2.x += r2.x; s2.y += r2.y;
        }
        // per-n scale: 2^(-L*|x|^2)
        float x2    = fmaf(xv.x, xv.x, xv.y * xv.y);
        float scale = fast_exp2(x2 * -LOG2E);

        float2* out2 = (float2*)out;
        out2[(size_t)0 * N + n] = make_float2(s0.x * scale, s0.y * scale);
        out2[(size_t)1 * N + n] = make_float2(s0.z * scale, s0.w * scale);
        out2[(size_t)2 * N + n] = make_float2(s1.x * scale, s1.y * scale);
        out2[(size_t)3 * N + n] = make_float2(s1.z * scale, s1.w * scale);
        out2[(size_t)4 * N + n] = make_float2(s2.x * scale, s2.y * scale);
    }
}

extern "C" void kernel_launch(void* const* d_in, const int* in_sizes, int n_in,
                              void* d_out, int out_size, void* d_ws, size_t ws_size,
                              hipStream_t stream) {
    const float* x       = (const float*)d_in[0];  // [N,2]
    const float* centers = (const float*)d_in[1];  // [256,2]
    const float* weights = (const float*)d_in[2];  // [5,256,2]
    float* out = (float*)d_out;                    // [5,N,2]

    int N = in_sizes[0] / 2;
    int grid = (N + 63) / 64;   // 64 n per block
    ensemble_rbf_kernel<<<grid, 256, 0, stream>>>(x, centers, weights, out, N);
}